// Round 7
// baseline (1374.261 us; speedup 1.0000x reference)
//
#include <hip/hip_runtime.h>
#include <hip/hip_fp16.h>

// Problem constants (fixed shapes from setup_inputs)
#define B_ 4
#define T_ 512
#define C_ 8
#define F_ 257
#define TAPS 5
#define DELAY 3
#define N_ 40          // TAPS*C
#define NA 48          // N_ + C_ (augmented: R | P)
#define AS 49          // padded aug row stride
#define TP 505         // T - DELAY - TAPS + 1
#define T0 7           // DELAY + TAPS - 1
#define BF (B_*F_)     // 1028
#define BTCF ((size_t)B_*T_*C_*F_)
#define YSH 532        // padded LDS row stride (f16x2 dwords): 532%32=20 -> c-rows hit distinct banks

typedef _Float16 half8 __attribute__((ext_vector_type(8)));
typedef float floatx4 __attribute__((ext_vector_type(4)));

union H8 { uint32_t u[4]; half8 v; };

__device__ inline uint32_t h2mul(uint32_t a, uint32_t b) {
    __half2 ha = *(__half2*)&a, hb = *(__half2*)&b;
    __half2 r = __hmul2(ha, hb);
    return *(uint32_t*)&r;
}
__device__ inline uint32_t packf16(float2 v) {
    __half hr = __float2half(v.x), hi = __float2half(v.y);
    return (uint32_t)__half_as_ushort(hr) | ((uint32_t)__half_as_ushort(hi) << 16);
}
__device__ inline float2 unpackf16(uint32_t u) {
    __half2 h = *(__half2*)&u;
    return make_float2(__low2float(h), __high2float(h));
}
// Build weighted X (re) / Y (im) f16 fragments from interleaved f16x2 + packed sqrt-weights.
__device__ inline void build_fr(const uint32_t* __restrict__ src, const uint32_t sw[4],
                                H8& X, H8& Y) {
#pragma unroll
    for (int p = 0; p < 4; ++p) {
        uint32_t d0 = src[2 * p], d1 = src[2 * p + 1];
        uint32_t xr = __builtin_amdgcn_perm(d1, d0, 0x05040100);  // (re_k, re_k+1)
        uint32_t yr = __builtin_amdgcn_perm(d1, d0, 0x07060302);  // (im_k, im_k+1)
        X.u[p] = h2mul(xr, sw[p]);
        Y.u[p] = h2mul(yr, sw[p]);
    }
}
// Zs row j -> dword offset into sYh: j<40: tap=j>>3,c=j&7 -> Y[c][k+4-tap]; j>=40: Y[j-40][k+7]
__device__ inline int zs_off(int j) {
    return (j < N_) ? (j & 7) * YSH + (4 - (j >> 3)) : (j - N_) * YSH + T0;
}

// ---------------- K1: (B,T,C,F) planar re/im -> (B,F,C,T) interleaved float2
__global__ __launch_bounds__(256) void k_transpose_in(const float* __restrict__ in_re,
                                                      const float* __restrict__ in_im,
                                                      float2* __restrict__ Y) {
    __shared__ float2 tile[32][33];
    int ft = blockIdx.x % 9;     // f tile
    int tt = blockIdx.x / 9;     // t tile
    int c = blockIdx.y, b = blockIdx.z;
    int tx = threadIdx.x, ty = threadIdx.y;
    int f = ft * 32 + tx;
#pragma unroll
    for (int i = 0; i < 4; ++i) {
        int t = tt * 32 + ty + i * 8;
        if (f < F_) {
            size_t idx = ((size_t)(b * T_ + t) * C_ + c) * F_ + f;
            tile[ty + i * 8][tx] = make_float2(in_re[idx], in_im[idx]);
        }
    }
    __syncthreads();
    int t2 = tt * 32 + tx;
#pragma unroll
    for (int i = 0; i < 4; ++i) {
        int f2 = ft * 32 + ty + i * 8;
        if (f2 < F_) {
            Y[((size_t)(b * F_ + f2) * C_ + c) * T_ + t2] = tile[tx][ty + i * 8];
        }
    }
}

// ---------------- K2 (fused): power + MFMA Gram build (f16 in, fp32 acc) +
//                 Gaussian solve (fp32, in-LDS) + tail filter; one block per (b,f).
//                 launch_bounds(256,3): bound 4 forced a 64-VGPR split and ~570MB of
//                 spill traffic per dispatch (R5/R6); bound 3 was spill-free in R4.
__global__ __launch_bounds__(256, 3) void k_fused(float2* __restrict__ Y,
                                                  float* __restrict__ pow_out) {
    __shared__ uint32_t sYh[C_ * YSH];               // 17024 B f16x2 (re,im)
    __shared__ float sPow[T_];                       //  2048 B
    __shared__ __align__(16) uint32_t sw_pk[256];    //  1024 B packed f16 sqrt-weight pairs
    __shared__ float2 sAug[N_ * AS];                 // 15680 B [40][49]
    __shared__ float2 sG[N_ * C_];                   //  2560 B [j][e]
    int bf = blockIdx.x;
    int tid = threadIdx.x;
    int t0 = tid, t1 = tid + 256;
    float2* Yp = Y + (size_t)bf * C_ * T_;

    // ---- stage: read Y (coalesced), write f16x2 LDS, fp32 power. No regs kept. ----
    {
        float s0 = 0.f, s1 = 0.f;
#pragma unroll
        for (int c = 0; c < C_; ++c) {
            float2 v0 = Yp[c * T_ + t0];
            float2 v1 = Yp[c * T_ + t1];
            sYh[c * YSH + t0] = packf16(v0);
            sYh[c * YSH + t1] = packf16(v1);
            s0 += v0.x * v0.x + v0.y * v0.y;
            s1 += v1.x * v1.x + v1.y * v1.y;
        }
        if (tid < YSH - T_) {
#pragma unroll
            for (int c = 0; c < C_; ++c) sYh[c * YSH + T_ + tid] = 0;  // zero pad (k overhang)
        }
        s0 = fmaxf(s0 * (1.0f / C_), 1e-6f);
        s1 = fmaxf(s1 * (1.0f / C_), 1e-6f);
        pow_out[(size_t)bf * T_ + t0] = s0;
        pow_out[(size_t)bf * T_ + t1] = s1;
        sPow[t0] = s0;
        sPow[t1] = s1;
    }
    __syncthreads();

    // ---- packed f16 sqrt(1/p[k+7]) weight pairs; zero for k >= TP (pads K to 512) ----
    {
        int k0 = 2 * tid, k1 = k0 + 1;
        float w0 = (k0 < TP) ? rsqrtf(sPow[k0 + T0]) : 0.f;   // p >= 1e-6 so max(p,1e-10)=p
        float w1 = (k1 < TP) ? rsqrtf(sPow[k1 + T0]) : 0.f;
        __half h0 = __float2half(w0), h1 = __float2half(w1);
        sw_pk[tid] = (uint32_t)__half_as_ushort(h0) | ((uint32_t)__half_as_ushort(h1) << 16);
    }
    __syncthreads();

    // ---- Gram via MFMA: G = Zs^H Zs (48x48, K=512). Waves 0..2 each own one 16-col strip. ----
    int wv = tid >> 6, ln = tid & 63;
    if (wv < 3) {
        int r16 = ln & 15, kg = ln >> 4;
        int offA[3];
#pragma unroll
        for (int mt = 0; mt < 3; ++mt) offA[mt] = zs_off(mt * 16 + r16);
        int offB = zs_off(wv * 16 + r16);
        floatx4 accRe[3], accIm[3];
#pragma unroll
        for (int mt = 0; mt < 3; ++mt) {
            accRe[mt] = (floatx4){0.f, 0.f, 0.f, 0.f};
            accIm[mt] = (floatx4){0.f, 0.f, 0.f, 0.f};
        }
        for (int ks = 0; ks < 16; ++ks) {
            int kbase = ks * 32 + kg * 8;
            uint32_t sw[4];
            {
                const uint4 sv = *(const uint4*)&sw_pk[kbase >> 1];
                sw[0] = sv.x; sw[1] = sv.y; sw[2] = sv.z; sw[3] = sv.w;
            }
            H8 Xb, Yb;
            build_fr(&sYh[offB + kbase], sw, Xb, Yb);
#pragma unroll
            for (int mt = 0; mt < 3; ++mt) {
                H8 Xa, Ya, nYa;
                build_fr(&sYh[offA[mt] + kbase], sw, Xa, Ya);
#pragma unroll
                for (int p = 0; p < 4; ++p) nYa.u[p] = Ya.u[p] ^ 0x80008000u;
                accRe[mt] = __builtin_amdgcn_mfma_f32_16x16x32_f16(Xa.v, Xb.v, accRe[mt], 0, 0, 0);
                accRe[mt] = __builtin_amdgcn_mfma_f32_16x16x32_f16(Ya.v, Yb.v, accRe[mt], 0, 0, 0);
                accIm[mt] = __builtin_amdgcn_mfma_f32_16x16x32_f16(Xa.v, Yb.v, accIm[mt], 0, 0, 0);
                accIm[mt] = __builtin_amdgcn_mfma_f32_16x16x32_f16(nYa.v, Xb.v, accIm[mt], 0, 0, 0);
            }
        }
        // C/D layout: col = lane&15, row = (lane>>4)*4 + reg  [m89-verified]
#pragma unroll
        for (int mt = 0; mt < 3; ++mt) {
#pragma unroll
            for (int r = 0; r < 4; ++r) {
                int m = mt * 16 + kg * 4 + r;
                if (m < N_)
                    sAug[m * AS + wv * 16 + r16] = make_float2(accRe[mt][r], accIm[mt][r]);
            }
        }
    }
    __syncthreads();

    // ---- diag loading ----
    if (tid == 0) {
        float tr = 0.f;
        for (int j = 0; j < N_; ++j) tr += sAug[j * AS + j].x;
        float ld = 1e-10f * tr / N_;
        for (int j = 0; j < N_; ++j) sAug[j * AS + j].x += ld;
    }
    __syncthreads();

    // ---- forward elimination (no pivot; HPD + diag loading) ----
    for (int p = 0; p < N_ - 1; ++p) {
        float2 piv = sAug[p * AS + p];
        float dnm = piv.x * piv.x + piv.y * piv.y;
        float pix = piv.x / dnm, piy = -piv.y / dnm;
        int nrows = N_ - 1 - p;
        int ncols = NA - 1 - p;
        int tot = nrows * ncols;
        for (int idx = tid; idx < tot; idx += 256) {
            int i = p + 1 + idx / ncols;
            int j = p + 1 + idx % ncols;
            float2 aip = sAug[i * AS + p];
            float mx = aip.x * pix - aip.y * piy;
            float my = aip.x * piy + aip.y * pix;
            float2 apj = sAug[p * AS + j];
            float2 v = sAug[i * AS + j];
            v.x -= mx * apj.x - my * apj.y;
            v.y -= mx * apj.y + my * apj.x;
            sAug[i * AS + j] = v;
        }
        __syncthreads();
    }
    // ---- backward elimination on RHS columns ----
    for (int p = N_ - 1; p > 0; --p) {
        float2 piv = sAug[p * AS + p];
        float dnm = piv.x * piv.x + piv.y * piv.y;
        float pix = piv.x / dnm, piy = -piv.y / dnm;
        int tot = p * C_;
        for (int idx = tid; idx < tot; idx += 256) {
            int i = idx / C_;
            int c = idx - i * C_;
            float2 rhs = sAug[p * AS + N_ + c];
            float xr = rhs.x * pix - rhs.y * piy;
            float xi = rhs.x * piy + rhs.y * pix;
            float2 aip = sAug[i * AS + p];
            float2 v = sAug[i * AS + N_ + c];
            v.x -= aip.x * xr - aip.y * xi;
            v.y -= aip.x * xi + aip.y * xr;
            sAug[i * AS + N_ + c] = v;
        }
        __syncthreads();
    }
    // ---- G[j][e] = RHS[j][e] / diag[j]  (320 entries > 256 threads: stride) ----
    for (int idx = tid; idx < N_ * C_; idx += 256) {
        int j = idx >> 3;
        int e = idx & 7;
        float2 piv = sAug[j * AS + j];
        float dnm = piv.x * piv.x + piv.y * piv.y;
        float pix = piv.x / dnm, piy = -piv.y / dnm;
        float2 rhs = sAug[j * AS + N_ + e];
        sG[idx] = make_float2(rhs.x * pix - rhs.y * piy, rhs.x * piy + rhs.y * pix);
    }
    __syncthreads();

    // ---- tail: enh[e,t] = Y[e,t] - sum_{tau,d} G[tau*8+d][e] * Y[d][t-3-tau] ----
    // Two sequential half-passes (t and t+256) to halve live accumulator registers.
#pragma unroll 1
    for (int half = 0; half < 2; ++half) {
        int t = tid + half * 256;
        float2 acc[C_];
#pragma unroll
        for (int e = 0; e < C_; ++e) acc[e] = make_float2(0.f, 0.f);
        for (int tau = 0; tau < TAPS; ++tau) {
            int s = t - DELAY - tau;
#pragma unroll
            for (int d = 0; d < C_; ++d) {
                float2 y = make_float2(0.f, 0.f);
                if (s >= 0) y = unpackf16(sYh[d * YSH + s]);
                const float2* gr = &sG[(tau * C_ + d) * C_];
#pragma unroll
                for (int e = 0; e < C_; ++e) {
                    float2 g = gr[e];
                    acc[e].x += g.x * y.x - g.y * y.y;
                    acc[e].y += g.x * y.y + g.y * y.x;
                }
            }
        }
#pragma unroll
        for (int e = 0; e < C_; ++e) {
            float2 c0 = Yp[e * T_ + t];
            Yp[e * T_ + t] = make_float2(c0.x - acc[e].x, c0.y - acc[e].y);
        }
    }
}

// ---------------- K3: (B,F,C,T) float2 -> (B,T,C,F) planar re/im with ilens mask
__global__ __launch_bounds__(256) void k_transpose_out(const float2* __restrict__ Yenh,
                                                       const int* __restrict__ ilens,
                                                       float* __restrict__ out_re,
                                                       float* __restrict__ out_im) {
    __shared__ float2 tile[32][33];
    int ft = blockIdx.x % 9;
    int tt = blockIdx.x / 9;
    int c = blockIdx.y, b = blockIdx.z;
    int tx = threadIdx.x, ty = threadIdx.y;
    int ilen = ilens[b];
    int t = tt * 32 + tx;
#pragma unroll
    for (int i = 0; i < 4; ++i) {
        int f = ft * 32 + ty + i * 8;
        if (f < F_) tile[tx][ty + i * 8] = Yenh[((size_t)(b * F_ + f) * C_ + c) * T_ + t];
    }
    __syncthreads();
    int f2 = ft * 32 + tx;
#pragma unroll
    for (int i = 0; i < 4; ++i) {
        int t2 = tt * 32 + ty + i * 8;
        if (f2 < F_) {
            float2 v = tile[ty + i * 8][tx];
            if (t2 >= ilen) v = make_float2(0.f, 0.f);
            size_t o = ((size_t)(b * T_ + t2) * C_ + c) * F_ + f2;
            out_re[o] = v.x;
            out_im[o] = v.y;
        }
    }
}

extern "C" void kernel_launch(void* const* d_in, const int* in_sizes, int n_in,
                              void* d_out, int out_size, void* d_ws, size_t ws_size,
                              hipStream_t stream) {
    const float* in_re = (const float*)d_in[0];
    const float* in_im = (const float*)d_in[1];
    const int* ilens = (const int*)d_in[2];

    float* out_re = (float*)d_out;
    float* out_im = out_re + BTCF;
    float* out_pw = out_im + BTCF;   // (B,F,T) float32

    // workspace: Y float2 (33.7MB)
    float2* Y = (float2*)d_ws;

    dim3 tb(32, 8);
    dim3 tg(9 * 16, C_, B_);   // 9 f-tiles x 16 t-tiles, C, B
    k_transpose_in<<<tg, tb, 0, stream>>>(in_re, in_im, Y);
    k_fused<<<BF, 256, 0, stream>>>(Y, out_pw);
    k_transpose_out<<<tg, tb, 0, stream>>>(Y, ilens, out_re, out_im);
}

// Round 8
// 252.199 us; speedup vs baseline: 5.4491x; 5.4491x over previous
//
#include <hip/hip_runtime.h>
#include <hip/hip_fp16.h>

// Problem constants (fixed shapes from setup_inputs)
#define B_ 4
#define T_ 512
#define C_ 8
#define F_ 257
#define TAPS 5
#define DELAY 3
#define N_ 40          // TAPS*C
#define NA 48          // N_ + C_ (augmented: R | P)
#define AS 49          // padded aug row stride
#define TP 505         // T - DELAY - TAPS + 1
#define T0 7           // DELAY + TAPS - 1
#define BF (B_*F_)     // 1028
#define BTCF ((size_t)B_*T_*C_*F_)
#define YSH 532        // padded LDS row stride (f16x2 dwords): covers k-overhang reads to t=518

typedef _Float16 half8 __attribute__((ext_vector_type(8)));
typedef float floatx4 __attribute__((ext_vector_type(4)));
typedef uint32_t uint32x4 __attribute__((ext_vector_type(4)));

// All helpers are pure SSA (no unions, no address-taken locals) so nothing
// can land in scratch. R5-R7 lost 0.6-3.4 GB/dispatch to private-segment
// traffic from union/reference-param/local-array patterns.

__device__ inline uint32_t h2mul(uint32_t a, uint32_t b) {
    __half2 r = __hmul2(__builtin_bit_cast(__half2, a), __builtin_bit_cast(__half2, b));
    return __builtin_bit_cast(uint32_t, r);
}
__device__ inline uint32_t packf16(float2 v) {
    __half2 h = __floats2half2_rn(v.x, v.y);
    return __builtin_bit_cast(uint32_t, h);
}
__device__ inline float2 unpackf16(uint32_t u) {
    __half2 h = __builtin_bit_cast(__half2, u);
    return make_float2(__low2float(h), __high2float(h));
}
__device__ inline half8 mkfrag(uint32_t a, uint32_t b, uint32_t c, uint32_t d) {
    uint32x4 v = {a, b, c, d};
    return __builtin_bit_cast(half8, v);
}

struct Frag { half8 X; half8 Y; };

// Build weighted re (X) / im (Y) f16 fragments from 8 consecutive interleaved
// f16x2 dwords at p, scaled by packed f16 weight pairs sw0..3. Pure value flow.
__device__ inline Frag build2(const uint32_t* p, uint32_t sw0, uint32_t sw1,
                              uint32_t sw2, uint32_t sw3) {
    uint32_t q0 = p[0], q1 = p[1], q2 = p[2], q3 = p[3];
    uint32_t q4 = p[4], q5 = p[5], q6 = p[6], q7 = p[7];
    uint32_t x0 = __builtin_amdgcn_perm(q1, q0, 0x05040100);
    uint32_t y0 = __builtin_amdgcn_perm(q1, q0, 0x07060302);
    uint32_t x1 = __builtin_amdgcn_perm(q3, q2, 0x05040100);
    uint32_t y1 = __builtin_amdgcn_perm(q3, q2, 0x07060302);
    uint32_t x2 = __builtin_amdgcn_perm(q5, q4, 0x05040100);
    uint32_t y2 = __builtin_amdgcn_perm(q5, q4, 0x07060302);
    uint32_t x3 = __builtin_amdgcn_perm(q7, q6, 0x05040100);
    uint32_t y3 = __builtin_amdgcn_perm(q7, q6, 0x07060302);
    Frag f;
    f.X = mkfrag(h2mul(x0, sw0), h2mul(x1, sw1), h2mul(x2, sw2), h2mul(x3, sw3));
    f.Y = mkfrag(h2mul(y0, sw0), h2mul(y1, sw1), h2mul(y2, sw2), h2mul(y3, sw3));
    return f;
}
// Zs row j -> dword offset into sYh: j<40: tap=j>>3,c=j&7 -> Y[c][k+4-tap]; j>=40: Y[j-40][k+7]
__device__ inline int zs_off(int j) {
    return (j < N_) ? (j & 7) * YSH + (4 - (j >> 3)) : (j - N_) * YSH + T0;
}

// ---------------- K1: (B,T,C,F) planar re/im -> (B,F,C,T) interleaved float2
__global__ __launch_bounds__(256) void k_transpose_in(const float* __restrict__ in_re,
                                                      const float* __restrict__ in_im,
                                                      float2* __restrict__ Y) {
    __shared__ float2 tile[32][33];
    int ft = blockIdx.x % 9;     // f tile
    int tt = blockIdx.x / 9;     // t tile
    int c = blockIdx.y, b = blockIdx.z;
    int tx = threadIdx.x, ty = threadIdx.y;
    int f = ft * 32 + tx;
#pragma unroll
    for (int i = 0; i < 4; ++i) {
        int t = tt * 32 + ty + i * 8;
        if (f < F_) {
            size_t idx = ((size_t)(b * T_ + t) * C_ + c) * F_ + f;
            tile[ty + i * 8][tx] = make_float2(in_re[idx], in_im[idx]);
        }
    }
    __syncthreads();
    int t2 = tt * 32 + tx;
#pragma unroll
    for (int i = 0; i < 4; ++i) {
        int f2 = ft * 32 + ty + i * 8;
        if (f2 < F_) {
            Y[((size_t)(b * F_ + f2) * C_ + c) * T_ + t2] = tile[tx][ty + i * 8];
        }
    }
}

// ---------------- K2 (fused): power + MFMA Gram build (f16 in, fp32 acc) +
//                 Gaussian solve (fp32, in-LDS) + tail filter; one block per (b,f).
__global__ __launch_bounds__(256) void k_fused(float2* __restrict__ Y,
                                               float* __restrict__ pow_out) {
    __shared__ uint32_t sYh[C_ * YSH];               // 17024 B f16x2 (re,im)
    __shared__ float sPow[T_];                       //  2048 B
    __shared__ __align__(16) uint32_t sw_pk[256];    //  1024 B packed f16 sqrt-weight pairs
    __shared__ float2 sAug[N_ * AS];                 // 15680 B [40][49]
    __shared__ float2 sG[N_ * C_];                   //  2560 B [j][e]
    int bf = blockIdx.x;
    int tid = threadIdx.x;
    int t0 = tid, t1 = tid + 256;
    float2* Yp = Y + (size_t)bf * C_ * T_;

    // ---- stage: read Y (coalesced), write f16x2 LDS, fp32 power. Scalars only. ----
    {
        float s0 = 0.f, s1 = 0.f;
#pragma unroll
        for (int c = 0; c < C_; ++c) {
            float2 v0 = Yp[c * T_ + t0];
            float2 v1 = Yp[c * T_ + t1];
            sYh[c * YSH + t0] = packf16(v0);
            sYh[c * YSH + t1] = packf16(v1);
            s0 += v0.x * v0.x + v0.y * v0.y;
            s1 += v1.x * v1.x + v1.y * v1.y;
        }
        if (tid < YSH - T_) {
#pragma unroll
            for (int c = 0; c < C_; ++c) sYh[c * YSH + T_ + tid] = 0;  // zero pad (k overhang)
        }
        s0 = fmaxf(s0 * (1.0f / C_), 1e-6f);
        s1 = fmaxf(s1 * (1.0f / C_), 1e-6f);
        pow_out[(size_t)bf * T_ + t0] = s0;
        pow_out[(size_t)bf * T_ + t1] = s1;
        sPow[t0] = s0;
        sPow[t1] = s1;
    }
    __syncthreads();

    // ---- packed f16 sqrt(1/p[k+7]) weight pairs; zero for k >= TP (pads K to 512) ----
    {
        int k0 = 2 * tid, k1 = k0 + 1;
        float w0 = (k0 < TP) ? rsqrtf(sPow[k0 + T0]) : 0.f;   // p >= 1e-6 so max(p,1e-10)=p
        float w1 = (k1 < TP) ? rsqrtf(sPow[k1 + T0]) : 0.f;
        sw_pk[tid] = packf16(make_float2(w0, w1));
    }
    __syncthreads();

    // ---- Gram via MFMA: G = Zs^H Zs (48x48, K=512). Wave wv owns 16-col strip;
    //      m-tiles processed one at a time to keep the live set ~50 VGPRs. ----
    int wv = tid >> 6, ln = tid & 63;
    if (wv < 3) {
        int r16 = ln & 15, kg = ln >> 4;
        int offB = zs_off(wv * 16 + r16);
#pragma unroll 1
        for (int mt = 0; mt < 3; ++mt) {
            int offA = zs_off(mt * 16 + r16);
            floatx4 aRe = {0.f, 0.f, 0.f, 0.f};
            floatx4 aIm = {0.f, 0.f, 0.f, 0.f};
            for (int ks = 0; ks < 16; ++ks) {
                int kbase = ks * 32 + kg * 8;
                uint32x4 sv = *(const uint32x4*)&sw_pk[kbase >> 1];
                Frag B = build2(&sYh[offB + kbase], sv[0], sv[1], sv[2], sv[3]);
                Frag A = build2(&sYh[offA + kbase], sv[0], sv[1], sv[2], sv[3]);
                half8 nYa = -A.Y;
                aRe = __builtin_amdgcn_mfma_f32_16x16x32_f16(A.X, B.X, aRe, 0, 0, 0);
                aRe = __builtin_amdgcn_mfma_f32_16x16x32_f16(A.Y, B.Y, aRe, 0, 0, 0);
                aIm = __builtin_amdgcn_mfma_f32_16x16x32_f16(A.X, B.Y, aIm, 0, 0, 0);
                aIm = __builtin_amdgcn_mfma_f32_16x16x32_f16(nYa, B.X, aIm, 0, 0, 0);
            }
            // C/D layout: col = lane&15, row = (lane>>4)*4 + reg  [m89-verified]
#pragma unroll
            for (int r = 0; r < 4; ++r) {
                int m = mt * 16 + kg * 4 + r;
                if (m < N_)
                    sAug[m * AS + wv * 16 + r16] = make_float2(aRe[r], aIm[r]);
            }
        }
    }
    __syncthreads();

    // ---- diag loading ----
    if (tid == 0) {
        float tr = 0.f;
        for (int j = 0; j < N_; ++j) tr += sAug[j * AS + j].x;
        float ld = 1e-10f * tr / N_;
        for (int j = 0; j < N_; ++j) sAug[j * AS + j].x += ld;
    }
    __syncthreads();

    // ---- forward elimination (no pivot; HPD + diag loading) ----
    for (int p = 0; p < N_ - 1; ++p) {
        float2 piv = sAug[p * AS + p];
        float dnm = piv.x * piv.x + piv.y * piv.y;
        float pix = piv.x / dnm, piy = -piv.y / dnm;
        int nrows = N_ - 1 - p;
        int ncols = NA - 1 - p;
        int tot = nrows * ncols;
        for (int idx = tid; idx < tot; idx += 256) {
            int i = p + 1 + idx / ncols;
            int j = p + 1 + idx % ncols;
            float2 aip = sAug[i * AS + p];
            float mx = aip.x * pix - aip.y * piy;
            float my = aip.x * piy + aip.y * pix;
            float2 apj = sAug[p * AS + j];
            float2 v = sAug[i * AS + j];
            v.x -= mx * apj.x - my * apj.y;
            v.y -= mx * apj.y + my * apj.x;
            sAug[i * AS + j] = v;
        }
        __syncthreads();
    }
    // ---- backward elimination on RHS columns ----
    for (int p = N_ - 1; p > 0; --p) {
        float2 piv = sAug[p * AS + p];
        float dnm = piv.x * piv.x + piv.y * piv.y;
        float pix = piv.x / dnm, piy = -piv.y / dnm;
        int tot = p * C_;
        for (int idx = tid; idx < tot; idx += 256) {
            int i = idx / C_;
            int c = idx - i * C_;
            float2 rhs = sAug[p * AS + N_ + c];
            float xr = rhs.x * pix - rhs.y * piy;
            float xi = rhs.x * piy + rhs.y * pix;
            float2 aip = sAug[i * AS + p];
            float2 v = sAug[i * AS + N_ + c];
            v.x -= aip.x * xr - aip.y * xi;
            v.y -= aip.x * xi + aip.y * xr;
            sAug[i * AS + N_ + c] = v;
        }
        __syncthreads();
    }
    // ---- G[j][e] = RHS[j][e] / diag[j]  (320 entries > 256 threads: stride) ----
    for (int idx = tid; idx < N_ * C_; idx += 256) {
        int j = idx >> 3;
        int e = idx & 7;
        float2 piv = sAug[j * AS + j];
        float dnm = piv.x * piv.x + piv.y * piv.y;
        float pix = piv.x / dnm, piy = -piv.y / dnm;
        float2 rhs = sAug[j * AS + N_ + e];
        sG[idx] = make_float2(rhs.x * pix - rhs.y * piy, rhs.x * piy + rhs.y * pix);
    }
    __syncthreads();

    // ---- tail: enh[e,t] = Y[e,t] - sum_{tau,d} G[tau*8+d][e] * Y[d][t-3-tau] ----
    // R4-proven scalar form: one (e,t) per loop step, scalar tr/ti accumulators,
    // fp32 direct term re-read from pristine global Y (coalesced).
    for (int idx = tid; idx < C_ * T_; idx += 256) {
        int e = idx >> 9;
        int t = idx & (T_ - 1);
        float2 cur = Yp[idx];
        float tr = 0.f, ti = 0.f;
        for (int tau = 0; tau < TAPS; ++tau) {
            int s = t - DELAY - tau;
            if (s < 0) break;  // larger tau => smaller s
#pragma unroll
            for (int d = 0; d < C_; ++d) {
                float2 g = sG[(tau * C_ + d) * C_ + e];
                float2 y = unpackf16(sYh[d * YSH + s]);
                tr += g.x * y.x - g.y * y.y;
                ti += g.x * y.y + g.y * y.x;
            }
        }
        Yp[idx] = make_float2(cur.x - tr, cur.y - ti);
    }
}

// ---------------- K3: (B,F,C,T) float2 -> (B,T,C,F) planar re/im with ilens mask
__global__ __launch_bounds__(256) void k_transpose_out(const float2* __restrict__ Yenh,
                                                       const int* __restrict__ ilens,
                                                       float* __restrict__ out_re,
                                                       float* __restrict__ out_im) {
    __shared__ float2 tile[32][33];
    int ft = blockIdx.x % 9;
    int tt = blockIdx.x / 9;
    int c = blockIdx.y, b = blockIdx.z;
    int tx = threadIdx.x, ty = threadIdx.y;
    int ilen = ilens[b];
    int t = tt * 32 + tx;
#pragma unroll
    for (int i = 0; i < 4; ++i) {
        int f = ft * 32 + ty + i * 8;
        if (f < F_) tile[tx][ty + i * 8] = Yenh[((size_t)(b * F_ + f) * C_ + c) * T_ + t];
    }
    __syncthreads();
    int f2 = ft * 32 + tx;
#pragma unroll
    for (int i = 0; i < 4; ++i) {
        int t2 = tt * 32 + ty + i * 8;
        if (f2 < F_) {
            float2 v = tile[ty + i * 8][tx];
            if (t2 >= ilen) v = make_float2(0.f, 0.f);
            size_t o = ((size_t)(b * T_ + t2) * C_ + c) * F_ + f2;
            out_re[o] = v.x;
            out_im[o] = v.y;
        }
    }
}

extern "C" void kernel_launch(void* const* d_in, const int* in_sizes, int n_in,
                              void* d_out, int out_size, void* d_ws, size_t ws_size,
                              hipStream_t stream) {
    const float* in_re = (const float*)d_in[0];
    const float* in_im = (const float*)d_in[1];
    const int* ilens = (const int*)d_in[2];

    float* out_re = (float*)d_out;
    float* out_im = out_re + BTCF;
    float* out_pw = out_im + BTCF;   // (B,F,T) float32

    // workspace: Y float2 (33.7MB)
    float2* Y = (float2*)d_ws;

    dim3 tb(32, 8);
    dim3 tg(9 * 16, C_, B_);   // 9 f-tiles x 16 t-tiles, C, B
    k_transpose_in<<<tg, tb, 0, stream>>>(in_re, in_im, Y);
    k_fused<<<BF, 256, 0, stream>>>(Y, out_pw);
    k_transpose_out<<<tg, tb, 0, stream>>>(Y, ilens, out_re, out_im);
}